// Round 12
// baseline (918.401 us; speedup 1.0000x reference)
//
#include <hip/hip_runtime.h>
#include <hip/hip_bf16.h>

typedef unsigned short u16;
typedef unsigned int   u32;
typedef __attribute__((ext_vector_type(8))) short short8;
typedef __attribute__((ext_vector_type(4))) float f32x4;
typedef __attribute__((ext_vector_type(4))) unsigned short u16x4;

#define E_    2048
#define H_    16
#define DH_   128
#define B_    2
#define T_    2048
#define NTOK  4096      // B*T
#define QKVN  6144      // 3*E

#define VMCNT(n) asm volatile("s_waitcnt vmcnt(" #n ")" ::: "memory")
#define LGKM0()  asm volatile("s_waitcnt lgkmcnt(0)" ::: "memory")

__device__ __forceinline__ u16 f2bf(float f) {
  union { float f; u32 u; } v; v.f = f;
  u32 r = (v.u + 0x7FFFu + ((v.u >> 16) & 1u)) >> 16;
  return (u16)r;
}

// ---------------------------------------------------------------- prep: coalesced 64x64 tile transpose
__global__ __launch_bounds__(256) void tr64(
    const float* __restrict__ in, u16* __restrict__ out,
    int R, int C, size_t inZ, size_t outZ)
{
  __shared__ float t[64][65];
  const float* ib = in + (size_t)blockIdx.z * inZ;
  u16* ob = out + (size_t)blockIdx.z * outZ;
  const int r0 = blockIdx.y * 64, c0 = blockIdx.x * 64;
  const int tid = threadIdx.x;
  const int rr = tid >> 4;
  const int cc = (tid & 15) * 4;
  #pragma unroll
  for (int p = 0; p < 4; ++p) {
    const float4 v = *(const float4*)(ib + (size_t)(r0 + p * 16 + rr) * C + c0 + cc);
    t[cc + 0][p * 16 + rr] = v.x;
    t[cc + 1][p * 16 + rr] = v.y;
    t[cc + 2][p * 16 + rr] = v.z;
    t[cc + 3][p * 16 + rr] = v.w;
  }
  __syncthreads();
  const int wr = tid >> 3;
  const int wc = (tid & 7) * 8;
  #pragma unroll
  for (int p = 0; p < 2; ++p) {
    short8 s;
    #pragma unroll
    for (int j = 0; j < 8; ++j) s[j] = (short)f2bf(t[p * 32 + wr][wc + j]);
    *(short8*)(ob + (size_t)(c0 + p * 32 + wr) * R + r0 + wc) = s;
  }
}

__global__ __launch_bounds__(256) void bias_cat(
    const float* __restrict__ bq, const float* __restrict__ bk,
    const float* __restrict__ bv, float* __restrict__ bias)
{
  int idx = blockIdx.x * 256 + threadIdx.x;   // 6144
  const float* bb = (idx < 2048) ? bq : (idx < 4096) ? bk : bv;
  bias[idx] = bb[idx & 2047];
}

// ---------------------------------------------------------------- rmsnorm
__global__ __launch_bounds__(256) void rmsnorm_k(
    const float* __restrict__ x, const float* __restrict__ g, u16* __restrict__ o)
{
  const int row = blockIdx.x;
  const float4* xr = (const float4*)(x + (size_t)row * E_);
  const float4* gr = (const float4*)g;
  const int tid = threadIdx.x;
  float4 a0 = xr[tid], a1 = xr[tid + 256];
  float s = a0.x*a0.x + a0.y*a0.y + a0.z*a0.z + a0.w*a0.w
          + a1.x*a1.x + a1.y*a1.y + a1.z*a1.z + a1.w*a1.w;
  #pragma unroll
  for (int m = 1; m < 64; m <<= 1) s += __shfl_xor(s, m);
  __shared__ float wsum[4];
  if ((tid & 63) == 0) wsum[tid >> 6] = s;
  __syncthreads();
  float tot = wsum[0] + wsum[1] + wsum[2] + wsum[3];
  float rinv = rsqrtf(tot * (1.0f / E_) + 1e-8f);
  float4 g0 = gr[tid], g1 = gr[tid + 256];
  u16x4 o0, o1;
  o0[0] = f2bf(a0.x * g0.x * rinv); o0[1] = f2bf(a0.y * g0.y * rinv);
  o0[2] = f2bf(a0.z * g0.z * rinv); o0[3] = f2bf(a0.w * g0.w * rinv);
  o1[0] = f2bf(a1.x * g1.x * rinv); o1[1] = f2bf(a1.y * g1.y * rinv);
  o1[2] = f2bf(a1.z * g1.z * rinv); o1[3] = f2bf(a1.w * g1.w * rinv);
  u16x4* orow = (u16x4*)(o + (size_t)row * E_);
  orow[tid] = o0;
  orow[tid + 256] = o1;
}

__device__ __forceinline__ void gload_lds16(const void* g, u16* lds_base) {
  __builtin_amdgcn_global_load_lds(
      (const __attribute__((address_space(1))) u32*)g,
      (__attribute__((address_space(3))) u32*)lds_base, 16, 0, 0);
}

// ---------------------------------------------------------------- gemmA: 128x128 tile, 256 thr, 2 LDS buffers (32KB)
// -> 5 blocks/CU (20 waves/CU): depth-1 prefetch + per-tile drain covered by
// cross-block wave overlap (m114). EPI: 0 bf16+bias, 1 f32+bias+resid,
// 2 bf16+bias+GELU, 3 = QKV (bf16 for Q/K cols; V cols written transposed to vt).
template<int MODE, int EPI>
__global__ __launch_bounds__(256, 5)
void gemmA(const u16* __restrict__ A, const u16* __restrict__ Bt,
           const float* __restrict__ bias, const float* __restrict__ resid,
           void* __restrict__ out, u16* __restrict__ vtout, int M, int N, int K)
{
  __shared__ __align__(16) u16 sh[2 * 8192];   // 32 KB

  const int tid  = threadIdx.x;
  const int lane = tid & 63;
  const int l15  = lane & 15, lg = lane >> 4;
  const int w    = tid >> 6;
  const int wm   = w >> 1;               // 0..1
  const int wn   = w & 1;                // 0..1
  const int xs   = (l15 >> 1) & 3;

  const int nbx = N >> 7;
  const int xcd = blockIdx.x & 7, j = blockIdx.x >> 3;
  int m0, n0;
  if constexpr (MODE == 1) {
    const int ncx = nbx >> 3;
    n0 = (xcd * ncx + j % ncx) << 7;
    m0 = (j / ncx) << 7;
  } else {
    const int nwg = nbx * (M >> 7);
    const int sid = xcd * (nwg >> 3) + j;
    m0 = (sid / nbx) << 7;
    n0 = (sid % nbx) << 7;
  }

  const int r0 = tid >> 2;
  const int c0 = (((tid & 3) ^ ((tid >> 3) & 3)) * 8);
  const u16* gA  = A  + (size_t)(m0 + r0) * K + c0;
  const u16* gB  = Bt + (size_t)(n0 + r0) * K + c0;
  const u16* gA2 = gA + (size_t)64 * K;
  const u16* gB2 = gB + (size_t)64 * K;
  const int wub = (tid & ~63) * 8;

  f32x4 acc[4][4] = {};
  const int NT = K >> 5;

  // prologue: stage tile 0 into buf 0
  gload_lds16(gA,  sh + wub);
  gload_lds16(gA2, sh + 2048 + wub);
  gload_lds16(gB,  sh + 4096 + wub);
  gload_lds16(gB2, sh + 6144 + wub);
  VMCNT(0);
  __builtin_amdgcn_s_barrier();

  int i = 0;

#define KTILE(CUR)                                                               \
  do {                                                                           \
    const u16* rb = sh + (CUR) * 8192;                                           \
    u16* wb = sh + (1 - (CUR)) * 8192;                                           \
    if (i + 1 < NT) {                                                            \
      const int kS = (i + 1) << 5;                                               \
      gload_lds16(gA  + kS, wb + wub);                                           \
      gload_lds16(gA2 + kS, wb + 2048 + wub);                                    \
      gload_lds16(gB  + kS, wb + 4096 + wub);                                    \
      gload_lds16(gB2 + kS, wb + 6144 + wub);                                    \
    }                                                                            \
    short8 af[4], bf[4];                                                         \
    _Pragma("unroll")                                                            \
    for (int n = 0; n < 4; ++n)                                                  \
      bf[n] = *(const short8*)(rb + 4096 + (wn * 64 + n * 16 + l15) * 32 + ((lg ^ xs) * 8)); \
    _Pragma("unroll")                                                            \
    for (int m = 0; m < 4; ++m)                                                  \
      af[m] = *(const short8*)(rb + (wm * 64 + m * 16 + l15) * 32 + ((lg ^ xs) * 8)); \
    _Pragma("unroll")                                                            \
    for (int m = 0; m < 4; ++m)                                                  \
      _Pragma("unroll")                                                          \
      for (int n = 0; n < 4; ++n)                                                \
        acc[m][n] = __builtin_amdgcn_mfma_f32_16x16x32_bf16(af[m], bf[n], acc[m][n], 0, 0, 0); \
    VMCNT(0);                                                                    \
    __builtin_amdgcn_s_barrier();                                                \
    ++i;                                                                         \
  } while (0)

  const int trips = NT >> 1;                 // NT even (64 / 256)
  #pragma unroll 1
  for (int t = 0; t < trips; ++t) {
    KTILE(0);
    KTILE(1);
  }
#undef KTILE

  // ---- epilogue (wave slice 64x64)
  float bv[4];
  #pragma unroll
  for (int n = 0; n < 4; ++n) bv[n] = bias[n0 + wn * 64 + n * 16 + l15];

  if constexpr (EPI == 1) {
    #pragma unroll
    for (int n = 0; n < 4; ++n) {
      const int col = n0 + wn * 64 + n * 16 + l15;
      #pragma unroll
      for (int m = 0; m < 4; ++m)
        #pragma unroll
        for (int r = 0; r < 4; ++r) {
          const int row = m0 + wm * 64 + m * 16 + lg * 4 + r;
          const size_t off = (size_t)row * N + col;
          ((float*)out)[off] = acc[m][n][r] + bv[n] + resid[off];
        }
    }
  } else if (EPI == 3 && n0 >= 4096) {
    // V section -> vt[b*16+h][d][t], via per-wave LDS transpose [64][64]
    u16* epb = sh + w * 4096;
    #pragma unroll
    for (int n = 0; n < 4; ++n)
      #pragma unroll
      for (int m = 0; m < 4; ++m)
        #pragma unroll
        for (int r = 0; r < 4; ++r)
          epb[(n * 16 + l15) * 64 + m * 16 + lg * 4 + r] = f2bf(acc[m][n][r] + bv[n]);
    LGKM0();
    const int colV0 = n0 - 4096 + wn * 64;
    const int hh = colV0 >> 7;
    const int db = colV0 & 127;
    const int tw = m0 + wm * 64;
    const int bb = tw >> 11;
    const int tb = tw & 2047;
    u16* vbase = vtout + ((size_t)(bb * 16 + hh) * 128 + db) * 2048 + tb;
    #pragma unroll
    for (int it = 0; it < 8; ++it) {
      const int c = it * 64 + lane;
      const int d = c >> 3, sl = c & 7;
      short8 s = *(const short8*)(epb + d * 64 + sl * 8);
      *(short8*)(vbase + (size_t)d * 2048 + sl * 8) = s;
    }
  } else {
    u16* ep = sh + w * 1024;
    #pragma unroll
    for (int m = 0; m < 4; ++m) {
      #pragma unroll
      for (int n = 0; n < 4; ++n)
        #pragma unroll
        for (int r = 0; r < 4; ++r) {
          float v = acc[m][n][r] + bv[n];
          if (EPI == 2) {
            float t = v * (0.79788456080286536f + 0.0356774081363231f * v * v);
            v = v / (1.0f + __expf(-2.0f * t));
          }
          ep[(lg * 4 + r) * 64 + n * 16 + l15] = f2bf(v);
        }
      LGKM0();
      const int row0 = m0 + wm * 64 + m * 16;
      #pragma unroll
      for (int it = 0; it < 2; ++it) {
        const int ch = it * 64 + lane;
        const int rr = ch >> 3, c8 = ch & 7;
        short8 s = *(const short8*)(ep + rr * 64 + c8 * 8);
        *(short8*)((u16*)out + (size_t)(row0 + rr) * N + n0 + wn * 64 + c8 * 8) = s;
      }
      LGKM0();
    }
  }
}

// ---------------------------------------------------------------- gemmB: 256x256, 512 thr, 3-buffer (R10-best, FFN1)
template<int MODE, int EPI>
__global__ __launch_bounds__(512, 2)
void gemmB(const u16* __restrict__ A, const u16* __restrict__ Bt,
           const float* __restrict__ bias, const float* __restrict__ resid,
           void* __restrict__ out, int M, int N, int K)
{
  constexpr int BUF = 16384;             // u16 per K-tile buffer (32 KB)
  __shared__ __align__(16) u16 sh[3 * BUF];

  const int tid  = threadIdx.x;
  const int lane = tid & 63;
  const int l15  = lane & 15, lg = lane >> 4;
  const int w    = tid >> 6;
  const int wm   = w >> 2;               // 0..1
  const int wn   = w & 3;                // 0..3
  const int xs   = (l15 >> 1) & 3;

  const int nbx = N >> 8;
  const int xcd = blockIdx.x & 7, j = blockIdx.x >> 3;
  int m0, n0;
  if constexpr (MODE == 1) {
    const int ncx = nbx >> 3;
    n0 = (xcd * ncx + j % ncx) << 8;
    m0 = (j / ncx) << 8;
  } else {
    const int nwg = nbx * (M >> 8);
    const int sid = xcd * (nwg >> 3) + j;
    m0 = (sid / nbx) << 8;
    n0 = (sid % nbx) << 8;
  }

  const int r0 = tid >> 2;
  const int c0 = (((tid & 3) ^ ((tid >> 3) & 3)) * 8);
  const u16* gA  = A  + (size_t)(m0 + r0) * K + c0;
  const u16* gB  = Bt + (size_t)(n0 + r0) * K + c0;
  const u16* gA2 = gA + (size_t)128 * K;
  const u16* gB2 = gB + (size_t)128 * K;
  const int wub = (tid & ~63) * 8;

  f32x4 acc[8][4] = {};
  const int NT = K >> 5;

  #pragma unroll
  for (int t = 0; t < 2; ++t) {
    u16* wb = sh + t * BUF;
    const int kS = t * 32;
    gload_lds16(gA  + kS, wb + wub);
    gload_lds16(gA2 + kS, wb + 4096 + wub);
    gload_lds16(gB  + kS, wb + 8192 + wub);
    gload_lds16(gB2 + kS, wb + 12288 + wub);
  }
  VMCNT(4);
  __builtin_amdgcn_s_barrier();

  int i = 0;

#define KTILE(CUR, STG)                                                          \
  do {                                                                           \
    const u16* rb = sh + (CUR) * BUF;                                            \
    u16* wb = sh + (STG) * BUF;                                                  \
    const bool st = (i + 2 < NT);                                                \
    const int kS = (i + 2) << 5;                                                 \
    const int rem = NT - 1 - i;                                                  \
    if (st) {                                                                    \
      gload_lds16(gA  + kS, wb + wub);                                           \
      gload_lds16(gA2 + kS, wb + 4096 + wub);                                    \
      gload_lds16(gB  + kS, wb + 8192 + wub);                                    \
      gload_lds16(gB2 + kS, wb + 12288 + wub);                                   \
    }                                                                            \
    short8 bf[4];                                                                \
    _Pragma("unroll")                                                            \
    for (int n = 0; n < 4; ++n)                                                  \
      bf[n] = *(const short8*)(rb + 8192 + (wn * 64 + n * 16 + l15) * 32 + ((lg ^ xs) * 8)); \
    _Pragma("unroll")                                                            \
    for (int mh = 0; mh < 2; ++mh) {                                             \
      short8 af[4];                                                              \
      _Pragma("unroll")                                                          \
      for (int m = 0; m < 4; ++m)                                                \
        af[m] = *(const short8*)(rb + (wm * 128 + (mh * 4 + m) * 16 + l15) * 32 + ((lg ^ xs) * 8)); \
      _Pragma("unroll")                                                          \
      for (int m = 0; m < 4; ++m)                                                \
        _Pragma("unroll")                                                        \
        for (int n = 0; n < 4; ++n)                                              \
          acc[mh * 4 + m][n] = __builtin_amdgcn_mfma_f32_16x16x32_bf16(af[m], bf[n], acc[mh * 4 + m][n], 0, 0, 0); \
    }                                                                            \
    if (rem >= 2) { VMCNT(4); } else { VMCNT(0); }                               \
    __builtin_amdgcn_s_barrier();                                                \
    ++i;                                                                         \
  } while (0)

  const int trips = NT / 3;
  #pragma unroll 1
  for (int t = 0; t < trips; ++t) {
    KTILE(0, 2);
    KTILE(1, 0);
    KTILE(2, 1);
  }
  if (i < NT) KTILE(0, 2);
  if (i < NT) KTILE(1, 0);
#undef KTILE

  float bv[4];
  #pragma unroll
  for (int n = 0; n < 4; ++n) bv[n] = bias[n0 + wn * 64 + n * 16 + l15];

  if constexpr (EPI == 1) {
    #pragma unroll
    for (int n = 0; n < 4; ++n) {
      const int col = n0 + wn * 64 + n * 16 + l15;
      #pragma unroll
      for (int m = 0; m < 8; ++m)
        #pragma unroll
        for (int r = 0; r < 4; ++r) {
          const int row = m0 + wm * 128 + m * 16 + lg * 4 + r;
          const size_t off = (size_t)row * N + col;
          ((float*)out)[off] = acc[m][n][r] + bv[n] + resid[off];
        }
    }
  } else {
    u16* ep = sh + w * 1024;
    #pragma unroll
    for (int m = 0; m < 8; ++m) {
      #pragma unroll
      for (int n = 0; n < 4; ++n)
        #pragma unroll
        for (int r = 0; r < 4; ++r) {
          float v = acc[m][n][r] + bv[n];
          if (EPI == 2) {
            float t = v * (0.79788456080286536f + 0.0356774081363231f * v * v);
            v = v / (1.0f + __expf(-2.0f * t));
          }
          ep[(lg * 4 + r) * 64 + n * 16 + l15] = f2bf(v);
        }
      LGKM0();
      const int row0 = m0 + wm * 128 + m * 16;
      #pragma unroll
      for (int it = 0; it < 2; ++it) {
        const int ch = it * 64 + lane;
        const int rr = ch >> 3, c8 = ch & 7;
        short8 s = *(const short8*)(ep + rr * 64 + c8 * 8);
        *(short8*)((u16*)out + (size_t)(row0 + rr) * N + n0 + wn * 64 + c8 * 8) = s;
      }
      LGKM0();
    }
  }
}

// ---------------------------------------------------------------- flash attention (causal)
__global__ __launch_bounds__(256) void attn_k(
    const u16* __restrict__ qkv, const u16* __restrict__ vt, u16* __restrict__ o)
{
  const int tid  = threadIdx.x;
  const int lane = tid & 63;
  const int w    = tid >> 6;
  const int l15  = lane & 15, lg = lane >> 4;
  const int bid  = blockIdx.x;
  const int pair = bid & 31;
  const int qt   = 15 - (bid >> 5);
  const int h    = pair & 15;
  const int b    = pair >> 4;
  const int Q0 = qt * 128;
  const int qw = Q0 + w * 32;

  __shared__ __align__(16) u16 Ks[2][64 * 128];
  __shared__ __align__(16) u16 Vs[2][128 * 64];
  __shared__ __align__(16) u16 Ps[4][32 * 64];

  const u16* qb  = qkv + (size_t)b * T_ * QKVN + h * DH_;
  const u16* kb  = qb + E_;
  const u16* vtb = vt + (size_t)(b * H_ + h) * DH_ * T_;

  short8 qf[2][4];
  #pragma unroll
  for (int qi = 0; qi < 2; ++qi)
    #pragma unroll
    for (int kk = 0; kk < 4; ++kk)
      qf[qi][kk] = *(const short8*)(qb + (size_t)(qw + qi * 16 + l15) * QKVN + kk * 32 + lg * 8);

  f32x4 oacc[2][8] = {};
  float m_[2][4], l_[2][4];
  #pragma unroll
  for (int qi = 0; qi < 2; ++qi)
    #pragma unroll
    for (int r = 0; r < 4; ++r) { m_[qi][r] = -1e30f; l_[qi][r] = 0.f; }

  const int xr = l15 & 7;
  const float scl = 0.08838834764831845f;
  const int nt = Q0 / 64 + 2;
  const int qmaxw = qw + 31;
  const int wub = (tid & ~63);

  const u16* kp[4]; const u16* vp[4];
  #pragma unroll
  for (int i = 0; i < 4; ++i) {
    int f = i * 256 + tid;
    int r = f >> 4, p = f & 15, c = p ^ (r & 7);
    kp[i] = kb + (size_t)r * QKVN + c * 8;
  }
  #pragma unroll
  for (int i = 0; i < 4; ++i) {
    int f = i * 256 + tid;
    int d = f >> 3, p = f & 7, c = p ^ (d & 7);
    vp[i] = vtb + (size_t)d * T_ + c * 8;
  }

  auto STAGEKV = [&](int s0, int bufi) {
    const size_t ko = (size_t)s0 * QKVN;
    #pragma unroll
    for (int i = 0; i < 4; ++i)
      gload_lds16(kp[i] + ko, &Ks[bufi][(i * 256 + wub) * 8]);
    #pragma unroll
    for (int i = 0; i < 4; ++i)
      gload_lds16(vp[i] + s0, &Vs[bufi][(i * 256 + wub) * 8]);
  };

  STAGEKV(0, 0);
  VMCNT(0);
  __builtin_amdgcn_s_barrier();

  #pragma unroll 1
  for (int st = 0; st < nt; ++st) {
    const int s0 = st * 64;
    const int cur = st & 1;
    if (st + 1 < nt) STAGEKV(s0 + 64, cur ^ 1);

    if (s0 <= qmaxw) {
      const u16* Kc = Ks[cur];
      const u16* Vc = Vs[cur];
      f32x4 sc[2][4] = {};
      __builtin_amdgcn_s_setprio(1);
      #pragma unroll
      for (int sj = 0; sj < 4; ++sj) {
        const int row = sj * 16 + l15;
        #pragma unroll
        for (int kk = 0; kk < 4; ++kk) {
          short8 kfr = *(const short8*)(Kc + row * 128 + (((kk * 4 + lg) ^ xr) * 8));
          sc[0][sj] = __builtin_amdgcn_mfma_f32_16x16x32_bf16(qf[0][kk], kfr, sc[0][sj], 0, 0, 0);
          sc[1][sj] = __builtin_amdgcn_mfma_f32_16x16x32_bf16(qf[1][kk], kfr, sc[1][sj], 0, 0, 0);
        }
      }
      __builtin_amdgcn_s_setprio(0);
      const bool needmask = (s0 + 63 > qw);
      #pragma unroll
      for (int qi = 0; qi < 2; ++qi)
        #pragma unroll
        for (int sj = 0; sj < 4; ++sj)
          #pragma unroll
          for (int r = 0; r < 4; ++r) {
            float v = sc[qi][sj][r] * scl;
            if (needmask) {
              int s = s0 + sj * 16 + l15;
              int q = qw + qi * 16 + lg * 4 + r;
              if (s > q) v = -1e30f;
            }
            sc[qi][sj][r] = v;
          }
      #pragma unroll
      for (int qi = 0; qi < 2; ++qi) {
        float tmax[4], alpha[4], rsum[4];
        #pragma unroll
        for (int r = 0; r < 4; ++r)
          tmax[r] = fmaxf(fmaxf(sc[qi][0][r], sc[qi][1][r]), fmaxf(sc[qi][2][r], sc[qi][3][r]));
        #pragma unroll
        for (int r = 0; r < 4; ++r)
          #pragma unroll
          for (int m = 1; m < 16; m <<= 1) tmax[r] = fmaxf(tmax[r], __shfl_xor(tmax[r], m));
        #pragma unroll
        for (int r = 0; r < 4; ++r) {
          float mn = fmaxf(m_[qi][r], tmax[r]);
          alpha[r] = __expf(m_[qi][r] - mn);
          m_[qi][r] = mn;
          rsum[r] = 0.f;
        }
        #pragma unroll
        for (int sj = 0; sj < 4; ++sj)
          #pragma unroll
          for (int r = 0; r < 4; ++r) {
            float p = __expf(sc[qi][sj][r] - m_[qi][r]);
            rsum[r] += p;
            const int row = qi * 16 + lg * 4 + r;
            const int ch  = (sj * 2 + (l15 >> 3)) ^ (row & 7);
            Ps[w][row * 64 + ch * 8 + (l15 & 7)] = f2bf(p);
          }
        #pragma unroll
        for (int r = 0; r < 4; ++r) {
          #pragma unroll
          for (int m = 1; m < 16; m <<= 1) rsum[r] += __shfl_xor(rsum[r], m);
          l_[qi][r] = l_[qi][r] * alpha[r] + rsum[r];
        }
        #pragma unroll
        for (int dj = 0; dj < 8; ++dj)
          #pragma unroll
          for (int r = 0; r < 4; ++r) oacc[qi][dj][r] *= alpha[r];
      }
      __builtin_amdgcn_s_setprio(1);
      #pragma unroll
      for (int ks = 0; ks < 2; ++ks) {
        short8 pf0 = *(const short8*)(&Ps[w][l15 * 64 + (((ks * 4 + lg) ^ xr) * 8)]);
        short8 pf1 = *(const short8*)(&Ps[w][(16 + l15) * 64 + (((ks * 4 + lg) ^ xr) * 8)]);
        #pragma unroll
        for (int dj = 0; dj < 8; ++dj) {
          const int row = dj * 16 + l15;
          short8 vfr = *(const short8*)(Vc + row * 64 + (((ks * 4 + lg) ^ xr) * 8));
          oacc[0][dj] = __builtin_amdgcn_mfma_f32_16x16x32_bf16(pf0, vfr, oacc[0][dj], 0, 0, 0);
          oacc[1][dj] = __builtin_amdgcn_mfma_f32_16x16x32_bf16(pf1, vfr, oacc[1][dj], 0, 0, 0);
        }
      }
      __builtin_amdgcn_s_setprio(0);
    }
    VMCNT(0);
    __builtin_amdgcn_s_barrier();
  }

  float inv[2][4];
  #pragma unroll
  for (int qi = 0; qi < 2; ++qi)
    #pragma unroll
    for (int r = 0; r < 4; ++r) inv[qi][r] = 1.0f / l_[qi][r];
  u16* ob = o + (size_t)(b * T_ + qw) * E_ + h * DH_;
  #pragma unroll
  for (int qi = 0; qi < 2; ++qi)
    #pragma unroll
    for (int dj = 0; dj < 8; ++dj)
      #pragma unroll
      for (int r = 0; r < 4; ++r)
        ob[(size_t)(qi * 16 + lg * 4 + r) * E_ + dj * 16 + l15] = f2bf(oacc[qi][dj][r] * inv[qi][r]);
}

// ---------------------------------------------------------------- launch
extern "C" void kernel_launch(void* const* d_in, const int* in_sizes, int n_in,
                              void* d_out, int out_size, void* d_ws, size_t ws_size,
                              hipStream_t stream)
{
  const float* x  = (const float*)d_in[0];
  const float* wq = (const float*)d_in[1];
  const float* bq = (const float*)d_in[2];
  const float* wk = (const float*)d_in[3];
  const float* bk = (const float*)d_in[4];
  const float* wv = (const float*)d_in[5];
  const float* bv = (const float*)d_in[6];
  const float* wo = (const float*)d_in[7];
  const float* bo = (const float*)d_in[8];
  const float* w1 = (const float*)d_in[9];
  const float* b1 = (const float*)d_in[10];
  const float* w2 = (const float*)d_in[11];
  const float* b2 = (const float*)d_in[12];
  const float* g1 = (const float*)d_in[13];
  const float* g2 = (const float*)d_in[14];
  float* xout = (float*)d_out;

  if (ws_size < 201351168u) return;   // need ~192 MB scratch

  char* ws = (char*)d_ws;
  u16*   wqkv_t = (u16*)(ws + 0);            // 25,165,824
  u16*   h1     = (u16*)(ws + 25165824);     // 16,777,216
  u16*   qkv    = (u16*)(ws + 41943040);     // 50,331,648
  u16*   vt     = (u16*)(ws + 92274688);     // 16,777,216
  u16*   o_     = (u16*)(ws + 109051904);    // 16,777,216
  u16*   wo_t   = (u16*)(ws + 125829120);    //  8,388,608
  u16*   w1_t   = (u16*)(ws + 134217728);    // 33,554,432
  u16*   w2_t   = (u16*)(ws + 167772160);    // 33,554,432
  float* bqkv   = (float*)(ws + 201326592);  //     24,576
  u16*   u_     = (u16*)(ws + 0);            // 67,108,864 (aliases dead prefix)
  u16*   h2     = vt;
  float* x2     = xout;

  tr64<<<dim3(2, 32, 16), 256, 0, stream>>>(wq, wqkv_t,                          E_, DH_, (size_t)E_ * DH_, (size_t)DH_ * E_);
  tr64<<<dim3(2, 32, 16), 256, 0, stream>>>(wk, wqkv_t + (size_t)E_ * E_,        E_, DH_, (size_t)E_ * DH_, (size_t)DH_ * E_);
  tr64<<<dim3(2, 32, 16), 256, 0, stream>>>(wv, wqkv_t + (size_t)2 * E_ * E_,    E_, DH_, (size_t)E_ * DH_, (size_t)DH_ * E_);
  tr64<<<dim3(32, 32, 1),  256, 0, stream>>>(wo, wo_t, E_, E_, 0, 0);
  tr64<<<dim3(128, 32, 1), 256, 0, stream>>>(w1, w1_t, E_, 4 * E_, 0, 0);
  tr64<<<dim3(32, 128, 1), 256, 0, stream>>>(w2, w2_t, 4 * E_, E_, 0, 0);
  bias_cat<<<24, 256, 0, stream>>>(bq, bk, bv, bqkv);

  rmsnorm_k<<<NTOK, 256, 0, stream>>>(x, g1, h1);
  // QKV: writes Q/K to qkv, V transposed to vt (vtrans fused)
  gemmA<1, 3><<<(NTOK / 128) * (QKVN / 128), 256, 0, stream>>>(h1, wqkv_t, bqkv, nullptr, qkv, vt, NTOK, QKVN, E_);
  attn_k<<<B_ * H_ * (T_ / 16 / 8), 256, 0, stream>>>(qkv, vt, o_);
  gemmA<0, 1><<<(NTOK / 128) * (E_ / 128), 256, 0, stream>>>(o_, wo_t, bo, x, x2, nullptr, NTOK, E_, E_);
  rmsnorm_k<<<NTOK, 256, 0, stream>>>(x2, g2, h2);
  gemmB<1, 2><<<(NTOK / 256) * (4 * E_ / 256), 512, 0, stream>>>(h2, w1_t, b1, nullptr, u_, NTOK, 4 * E_, E_);
  gemmA<0, 1><<<(NTOK / 128) * (E_ / 128), 256, 0, stream>>>(u_, w2_t, b2, x2, xout, nullptr, NTOK, E_, 4 * E_);
}

// Round 13
// 667.322 us; speedup vs baseline: 1.3762x; 1.3762x over previous
//
#include <hip/hip_runtime.h>
#include <hip/hip_bf16.h>

typedef unsigned short u16;
typedef unsigned int   u32;
typedef __attribute__((ext_vector_type(8))) short short8;
typedef __attribute__((ext_vector_type(4))) float f32x4;
typedef __attribute__((ext_vector_type(4))) unsigned short u16x4;

#define E_    2048
#define H_    16
#define DH_   128
#define B_    2
#define T_    2048
#define NTOK  4096      // B*T
#define QKVN  6144      // 3*E

#define VMCNT(n) asm volatile("s_waitcnt vmcnt(" #n ")" ::: "memory")
#define LGKM0()  asm volatile("s_waitcnt lgkmcnt(0)" ::: "memory")

__device__ __forceinline__ u16 f2bf(float f) {
  union { float f; u32 u; } v; v.f = f;
  u32 r = (v.u + 0x7FFFu + ((v.u >> 16) & 1u)) >> 16;
  return (u16)r;
}

// ---------------------------------------------------------------- prep: coalesced 64x64 tile transpose
__global__ __launch_bounds__(256) void tr64(
    const float* __restrict__ in, u16* __restrict__ out,
    int R, int C, size_t inZ, size_t outZ)
{
  __shared__ float t[64][65];
  const float* ib = in + (size_t)blockIdx.z * inZ;
  u16* ob = out + (size_t)blockIdx.z * outZ;
  const int r0 = blockIdx.y * 64, c0 = blockIdx.x * 64;
  const int tid = threadIdx.x;
  const int rr = tid >> 4;
  const int cc = (tid & 15) * 4;
  #pragma unroll
  for (int p = 0; p < 4; ++p) {
    const float4 v = *(const float4*)(ib + (size_t)(r0 + p * 16 + rr) * C + c0 + cc);
    t[cc + 0][p * 16 + rr] = v.x;
    t[cc + 1][p * 16 + rr] = v.y;
    t[cc + 2][p * 16 + rr] = v.z;
    t[cc + 3][p * 16 + rr] = v.w;
  }
  __syncthreads();
  const int wr = tid >> 3;
  const int wc = (tid & 7) * 8;
  #pragma unroll
  for (int p = 0; p < 2; ++p) {
    short8 s;
    #pragma unroll
    for (int j = 0; j < 8; ++j) s[j] = (short)f2bf(t[p * 32 + wr][wc + j]);
    *(short8*)(ob + (size_t)(c0 + p * 32 + wr) * R + r0 + wc) = s;
  }
}

__global__ __launch_bounds__(256) void bias_cat(
    const float* __restrict__ bq, const float* __restrict__ bk,
    const float* __restrict__ bv, float* __restrict__ bias)
{
  int idx = blockIdx.x * 256 + threadIdx.x;   // 6144
  const float* bb = (idx < 2048) ? bq : (idx < 4096) ? bk : bv;
  bias[idx] = bb[idx & 2047];
}

// ---------------------------------------------------------------- rmsnorm
__global__ __launch_bounds__(256) void rmsnorm_k(
    const float* __restrict__ x, const float* __restrict__ g, u16* __restrict__ o)
{
  const int row = blockIdx.x;
  const float4* xr = (const float4*)(x + (size_t)row * E_);
  const float4* gr = (const float4*)g;
  const int tid = threadIdx.x;
  float4 a0 = xr[tid], a1 = xr[tid + 256];
  float s = a0.x*a0.x + a0.y*a0.y + a0.z*a0.z + a0.w*a0.w
          + a1.x*a1.x + a1.y*a1.y + a1.z*a1.z + a1.w*a1.w;
  #pragma unroll
  for (int m = 1; m < 64; m <<= 1) s += __shfl_xor(s, m);
  __shared__ float wsum[4];
  if ((tid & 63) == 0) wsum[tid >> 6] = s;
  __syncthreads();
  float tot = wsum[0] + wsum[1] + wsum[2] + wsum[3];
  float rinv = rsqrtf(tot * (1.0f / E_) + 1e-8f);
  float4 g0 = gr[tid], g1 = gr[tid + 256];
  u16x4 o0, o1;
  o0[0] = f2bf(a0.x * g0.x * rinv); o0[1] = f2bf(a0.y * g0.y * rinv);
  o0[2] = f2bf(a0.z * g0.z * rinv); o0[3] = f2bf(a0.w * g0.w * rinv);
  o1[0] = f2bf(a1.x * g1.x * rinv); o1[1] = f2bf(a1.y * g1.y * rinv);
  o1[2] = f2bf(a1.z * g1.z * rinv); o1[3] = f2bf(a1.w * g1.w * rinv);
  u16x4* orow = (u16x4*)(o + (size_t)row * E_);
  orow[tid] = o0;
  orow[tid + 256] = o1;
}

__device__ __forceinline__ void gload_lds16(const void* g, u16* lds_base) {
  __builtin_amdgcn_global_load_lds(
      (const __attribute__((address_space(1))) u32*)g,
      (__attribute__((address_space(3))) u32*)lds_base, 16, 0, 0);
}

// ---------------------------------------------------------------- GEMM: R10-best. 512 thr, 3-buffer counted-vmcnt,
// single-region K-tile, XOR swizzle, MODE XCD partitioning.
// EPI: 0 bf16+bias, 1 f32+bias+resid, 2 bf16+bias+GELU,
//      3 QKV fused: Q/K cols -> out (bf16), V cols -> vtout transposed.
template<int BM, int BN, int MODE, int EPI>
__global__ __launch_bounds__(512, 2)
void gemm3(const u16* __restrict__ A, const u16* __restrict__ Bt,
           const float* __restrict__ bias, const float* __restrict__ resid,
           void* __restrict__ out, u16* __restrict__ vtout, int M, int N, int K)
{
  constexpr int WROWS = BM / 2;          // 128 or 64
  constexpr int WCOLS = BN / 4;          // 64
  constexpr int MR    = WROWS / 16;      // 8 or 4
  constexpr int BUF   = (BM + BN) * 32;  // u16 per K-tile buffer
  __shared__ __align__(16) u16 sh[3 * BUF];

  const int tid  = threadIdx.x;
  const int lane = tid & 63;
  const int l15  = lane & 15, lg = lane >> 4;
  const int w    = tid >> 6;
  const int wm   = w >> 2;
  const int wn   = w & 3;
  const int xs   = (l15 >> 1) & 3;

  const int nbx = N / BN;
  const int xcd = blockIdx.x & 7, j = blockIdx.x >> 3;
  int m0, n0;
  if constexpr (MODE == 1) {
    const int ncx = nbx >> 3;
    n0 = (xcd * ncx + j % ncx) * BN;
    m0 = (j / ncx) * BM;
  } else {
    const int nwg = nbx * (M / BM);
    const int sid = xcd * (nwg >> 3) + j;
    m0 = (sid / nbx) * BM;
    n0 = (sid % nbx) * BN;
  }

  const int r0 = tid >> 2;
  const int c0 = (((tid & 3) ^ ((tid >> 3) & 3)) * 8);
  const u16* gA  = A  + (size_t)(m0 + r0) * K + c0;
  const u16* gB  = Bt + (size_t)(n0 + r0) * K + c0;
  const u16* gA2 = gA + (size_t)128 * K;
  const u16* gB2 = gB + (size_t)128 * K;
  const int wub = (tid & ~63) * 8;

  f32x4 acc[MR][4] = {};
  const int NT = K >> 5;

  #pragma unroll
  for (int t = 0; t < 2; ++t) {
    u16* wb = sh + t * BUF;
    const int kS = t * 32;
    if constexpr (BM == 256) {
      gload_lds16(gA  + kS, wb + wub);
      gload_lds16(gA2 + kS, wb + 4096 + wub);
      gload_lds16(gB  + kS, wb + 8192 + wub);
      gload_lds16(gB2 + kS, wb + 12288 + wub);
    } else {
      gload_lds16(gA  + kS, wb + wub);
      gload_lds16(gB  + kS, wb + 4096 + wub);
      gload_lds16(gB2 + kS, wb + 8192 + wub);
    }
  }
  if constexpr (BM == 256) VMCNT(4); else VMCNT(3);
  __builtin_amdgcn_s_barrier();

  int i = 0;

#define KTILE(CUR, STG)                                                          \
  do {                                                                           \
    const u16* rb = sh + (CUR) * BUF;                                            \
    u16* wb = sh + (STG) * BUF;                                                  \
    const bool st = (i + 2 < NT);                                                \
    const int kS = (i + 2) << 5;                                                 \
    const int rem = NT - 1 - i;                                                  \
    if (st) {                                                                    \
      if constexpr (BM == 256) {                                                 \
        gload_lds16(gA  + kS, wb + wub);                                         \
        gload_lds16(gA2 + kS, wb + 4096 + wub);                                  \
        gload_lds16(gB  + kS, wb + 8192 + wub);                                  \
        gload_lds16(gB2 + kS, wb + 12288 + wub);                                 \
      } else {                                                                   \
        gload_lds16(gA  + kS, wb + wub);                                         \
        gload_lds16(gB  + kS, wb + 4096 + wub);                                  \
        gload_lds16(gB2 + kS, wb + 8192 + wub);                                  \
      }                                                                          \
    }                                                                            \
    short8 bf[4];                                                                \
    _Pragma("unroll")                                                            \
    for (int n = 0; n < 4; ++n)                                                  \
      bf[n] = *(const short8*)(rb + BM * 32 + (wn * WCOLS + n * 16 + l15) * 32 + ((lg ^ xs) * 8)); \
    _Pragma("unroll")                                                            \
    for (int mh = 0; mh < MR / 4; ++mh) {                                        \
      short8 af[4];                                                              \
      _Pragma("unroll")                                                          \
      for (int m = 0; m < 4; ++m)                                                \
        af[m] = *(const short8*)(rb + (wm * WROWS + (mh * 4 + m) * 16 + l15) * 32 + ((lg ^ xs) * 8)); \
      _Pragma("unroll")                                                          \
      for (int m = 0; m < 4; ++m)                                                \
        _Pragma("unroll")                                                        \
        for (int n = 0; n < 4; ++n)                                              \
          acc[mh * 4 + m][n] = __builtin_amdgcn_mfma_f32_16x16x32_bf16(af[m], bf[n], acc[mh * 4 + m][n], 0, 0, 0); \
    }                                                                            \
    if (rem >= 2) { if constexpr (BM == 256) { VMCNT(4); } else { VMCNT(3); } }  \
    else { VMCNT(0); }                                                           \
    __builtin_amdgcn_s_barrier();                                                \
    ++i;                                                                         \
  } while (0)

  const int trips = NT / 3;                 // NT = 64 or 256 -> remainder 1
  #pragma unroll 1
  for (int t = 0; t < trips; ++t) {
    KTILE(0, 2);
    KTILE(1, 0);
    KTILE(2, 1);
  }
  if (i < NT) KTILE(0, 2);
  if (i < NT) KTILE(1, 0);
#undef KTILE

  // ---- epilogue
  float bv[4];
  #pragma unroll
  for (int n = 0; n < 4; ++n) bv[n] = bias[n0 + wn * WCOLS + n * 16 + l15];

  if constexpr (EPI == 1) {
    #pragma unroll
    for (int n = 0; n < 4; ++n) {
      const int col = n0 + wn * WCOLS + n * 16 + l15;
      #pragma unroll
      for (int m = 0; m < MR; ++m)
        #pragma unroll
        for (int r = 0; r < 4; ++r) {
          const int row = m0 + wm * WROWS + m * 16 + lg * 4 + r;
          const size_t off = (size_t)row * N + col;
          ((float*)out)[off] = acc[m][n][r] + bv[n] + resid[off];
        }
    }
  } else if (EPI == 3 && n0 >= 4096) {
    // V section -> vt[b*16+h][d][t], via per-wave LDS transpose [64][64]
    u16* epb = sh + w * 4096;              // 8 waves x 8 KB = 64 KB <= 72 KB
    #pragma unroll
    for (int n = 0; n < 4; ++n)
      #pragma unroll
      for (int m = 0; m < MR; ++m)
        #pragma unroll
        for (int r = 0; r < 4; ++r)
          epb[(n * 16 + l15) * 64 + m * 16 + lg * 4 + r] = f2bf(acc[m][n][r] + bv[n]);
    LGKM0();
    const int colV0 = n0 - 4096 + wn * 64; // d-block within [b,h]
    const int hh = colV0 >> 7;
    const int db = colV0 & 127;
    const int tw = m0 + wm * WROWS;        // token base of this wave's rows
    const int bb = tw >> 11;
    const int tb = tw & 2047;
    u16* vbase = vtout + ((size_t)(bb * 16 + hh) * 128 + db) * 2048 + tb;
    #pragma unroll
    for (int it = 0; it < 8; ++it) {
      const int c = it * 64 + lane;
      const int d = c >> 3, sl = c & 7;
      short8 s = *(const short8*)(epb + d * 64 + sl * 8);
      *(short8*)(vbase + (size_t)d * 2048 + sl * 8) = s;
    }
  } else {
    // bf16 out staged via per-wave LDS, contiguous short8 stores
    u16* ep = sh + w * 1024;
    #pragma unroll
    for (int m = 0; m < MR; ++m) {
      #pragma unroll
      for (int n = 0; n < 4; ++n)
        #pragma unroll
        for (int r = 0; r < 4; ++r) {
          float v = acc[m][n][r] + bv[n];
          if (EPI == 2) {
            float t = v * (0.79788456080286536f + 0.0356774081363231f * v * v);
            v = v / (1.0f + __expf(-2.0f * t));
          }
          ep[(lg * 4 + r) * 64 + n * 16 + l15] = f2bf(v);
        }
      LGKM0();
      const int row0 = m0 + wm * WROWS + m * 16;
      #pragma unroll
      for (int it = 0; it < 2; ++it) {
        const int ch = it * 64 + lane;
        const int rr = ch >> 3, c8 = ch & 7;
        short8 s = *(const short8*)(ep + rr * 64 + c8 * 8);
        *(short8*)((u16*)out + (size_t)(row0 + rr) * N + n0 + wn * WCOLS + c8 * 8) = s;
      }
      LGKM0();
    }
  }
}

// ---------------------------------------------------------------- flash attention (causal)
__global__ __launch_bounds__(256) void attn_k(
    const u16* __restrict__ qkv, const u16* __restrict__ vt, u16* __restrict__ o)
{
  const int tid  = threadIdx.x;
  const int lane = tid & 63;
  const int w    = tid >> 6;
  const int l15  = lane & 15, lg = lane >> 4;
  const int bid  = blockIdx.x;
  const int pair = bid & 31;
  const int qt   = 15 - (bid >> 5);
  const int h    = pair & 15;
  const int b    = pair >> 4;
  const int Q0 = qt * 128;
  const int qw = Q0 + w * 32;

  __shared__ __align__(16) u16 Ks[2][64 * 128];
  __shared__ __align__(16) u16 Vs[2][128 * 64];
  __shared__ __align__(16) u16 Ps[4][32 * 64];

  const u16* qb  = qkv + (size_t)b * T_ * QKVN + h * DH_;
  const u16* kb  = qb + E_;
  const u16* vtb = vt + (size_t)(b * H_ + h) * DH_ * T_;

  short8 qf[2][4];
  #pragma unroll
  for (int qi = 0; qi < 2; ++qi)
    #pragma unroll
    for (int kk = 0; kk < 4; ++kk)
      qf[qi][kk] = *(const short8*)(qb + (size_t)(qw + qi * 16 + l15) * QKVN + kk * 32 + lg * 8);

  f32x4 oacc[2][8] = {};
  float m_[2][4], l_[2][4];
  #pragma unroll
  for (int qi = 0; qi < 2; ++qi)
    #pragma unroll
    for (int r = 0; r < 4; ++r) { m_[qi][r] = -1e30f; l_[qi][r] = 0.f; }

  const int xr = l15 & 7;
  const float scl = 0.08838834764831845f;
  const int nt = Q0 / 64 + 2;
  const int qmaxw = qw + 31;
  const int wub = (tid & ~63);

  const u16* kp[4]; const u16* vp[4];
  #pragma unroll
  for (int i = 0; i < 4; ++i) {
    int f = i * 256 + tid;
    int r = f >> 4, p = f & 15, c = p ^ (r & 7);
    kp[i] = kb + (size_t)r * QKVN + c * 8;
  }
  #pragma unroll
  for (int i = 0; i < 4; ++i) {
    int f = i * 256 + tid;
    int d = f >> 3, p = f & 7, c = p ^ (d & 7);
    vp[i] = vtb + (size_t)d * T_ + c * 8;
  }

  auto STAGEKV = [&](int s0, int bufi) {
    const size_t ko = (size_t)s0 * QKVN;
    #pragma unroll
    for (int i = 0; i < 4; ++i)
      gload_lds16(kp[i] + ko, &Ks[bufi][(i * 256 + wub) * 8]);
    #pragma unroll
    for (int i = 0; i < 4; ++i)
      gload_lds16(vp[i] + s0, &Vs[bufi][(i * 256 + wub) * 8]);
  };

  STAGEKV(0, 0);
  VMCNT(0);
  __builtin_amdgcn_s_barrier();

  #pragma unroll 1
  for (int st = 0; st < nt; ++st) {
    const int s0 = st * 64;
    const int cur = st & 1;
    if (st + 1 < nt) STAGEKV(s0 + 64, cur ^ 1);

    if (s0 <= qmaxw) {
      const u16* Kc = Ks[cur];
      const u16* Vc = Vs[cur];
      f32x4 sc[2][4] = {};
      __builtin_amdgcn_s_setprio(1);
      #pragma unroll
      for (int sj = 0; sj < 4; ++sj) {
        const int row = sj * 16 + l15;
        #pragma unroll
        for (int kk = 0; kk < 4; ++kk) {
          short8 kfr = *(const short8*)(Kc + row * 128 + (((kk * 4 + lg) ^ xr) * 8));
          sc[0][sj] = __builtin_amdgcn_mfma_f32_16x16x32_bf16(qf[0][kk], kfr, sc[0][sj], 0, 0, 0);
          sc[1][sj] = __builtin_amdgcn_mfma_f32_16x16x32_bf16(qf[1][kk], kfr, sc[1][sj], 0, 0, 0);
        }
      }
      __builtin_amdgcn_s_setprio(0);
      const bool needmask = (s0 + 63 > qw);
      #pragma unroll
      for (int qi = 0; qi < 2; ++qi)
        #pragma unroll
        for (int sj = 0; sj < 4; ++sj)
          #pragma unroll
          for (int r = 0; r < 4; ++r) {
            float v = sc[qi][sj][r] * scl;
            if (needmask) {
              int s = s0 + sj * 16 + l15;
              int q = qw + qi * 16 + lg * 4 + r;
              if (s > q) v = -1e30f;
            }
            sc[qi][sj][r] = v;
          }
      #pragma unroll
      for (int qi = 0; qi < 2; ++qi) {
        float tmax[4], alpha[4], rsum[4];
        #pragma unroll
        for (int r = 0; r < 4; ++r)
          tmax[r] = fmaxf(fmaxf(sc[qi][0][r], sc[qi][1][r]), fmaxf(sc[qi][2][r], sc[qi][3][r]));
        #pragma unroll
        for (int r = 0; r < 4; ++r)
          #pragma unroll
          for (int m = 1; m < 16; m <<= 1) tmax[r] = fmaxf(tmax[r], __shfl_xor(tmax[r], m));
        #pragma unroll
        for (int r = 0; r < 4; ++r) {
          float mn = fmaxf(m_[qi][r], tmax[r]);
          alpha[r] = __expf(m_[qi][r] - mn);
          m_[qi][r] = mn;
          rsum[r] = 0.f;
        }
        #pragma unroll
        for (int sj = 0; sj < 4; ++sj)
          #pragma unroll
          for (int r = 0; r < 4; ++r) {
            float p = __expf(sc[qi][sj][r] - m_[qi][r]);
            rsum[r] += p;
            const int row = qi * 16 + lg * 4 + r;
            const int ch  = (sj * 2 + (l15 >> 3)) ^ (row & 7);
            Ps[w][row * 64 + ch * 8 + (l15 & 7)] = f2bf(p);
          }
        #pragma unroll
        for (int r = 0; r < 4; ++r) {
          #pragma unroll
          for (int m = 1; m < 16; m <<= 1) rsum[r] += __shfl_xor(rsum[r], m);
          l_[qi][r] = l_[qi][r] * alpha[r] + rsum[r];
        }
        #pragma unroll
        for (int dj = 0; dj < 8; ++dj)
          #pragma unroll
          for (int r = 0; r < 4; ++r) oacc[qi][dj][r] *= alpha[r];
      }
      __builtin_amdgcn_s_setprio(1);
      #pragma unroll
      for (int ks = 0; ks < 2; ++ks) {
        short8 pf0 = *(const short8*)(&Ps[w][l15 * 64 + (((ks * 4 + lg) ^ xr) * 8)]);
        short8 pf1 = *(const short8*)(&Ps[w][(16 + l15) * 64 + (((ks * 4 + lg) ^ xr) * 8)]);
        #pragma unroll
        for (int dj = 0; dj < 8; ++dj) {
          const int row = dj * 16 + l15;
          short8 vfr = *(const short8*)(Vc + row * 64 + (((ks * 4 + lg) ^ xr) * 8));
          oacc[0][dj] = __builtin_amdgcn_mfma_f32_16x16x32_bf16(pf0, vfr, oacc[0][dj], 0, 0, 0);
          oacc[1][dj] = __builtin_amdgcn_mfma_f32_16x16x32_bf16(pf1, vfr, oacc[1][dj], 0, 0, 0);
        }
      }
      __builtin_amdgcn_s_setprio(0);
    }
    VMCNT(0);
    __builtin_amdgcn_s_barrier();
  }

  float inv[2][4];
  #pragma unroll
  for (int qi = 0; qi < 2; ++qi)
    #pragma unroll
    for (int r = 0; r < 4; ++r) inv[qi][r] = 1.0f / l_[qi][r];
  u16* ob = o + (size_t)(b * T_ + qw) * E_ + h * DH_;
  #pragma unroll
  for (int qi = 0; qi < 2; ++qi)
    #pragma unroll
    for (int dj = 0; dj < 8; ++dj)
      #pragma unroll
      for (int r = 0; r < 4; ++r)
        ob[(size_t)(qi * 16 + lg * 4 + r) * E_ + dj * 16 + l15] = f2bf(oacc[qi][dj][r] * inv[qi][r]);
}

// ---------------------------------------------------------------- launch
extern "C" void kernel_launch(void* const* d_in, const int* in_sizes, int n_in,
                              void* d_out, int out_size, void* d_ws, size_t ws_size,
                              hipStream_t stream)
{
  const float* x  = (const float*)d_in[0];
  const float* wq = (const float*)d_in[1];
  const float* bq = (const float*)d_in[2];
  const float* wk = (const float*)d_in[3];
  const float* bk = (const float*)d_in[4];
  const float* wv = (const float*)d_in[5];
  const float* bv = (const float*)d_in[6];
  const float* wo = (const float*)d_in[7];
  const float* bo = (const float*)d_in[8];
  const float* w1 = (const float*)d_in[9];
  const float* b1 = (const float*)d_in[10];
  const float* w2 = (const float*)d_in[11];
  const float* b2 = (const float*)d_in[12];
  const float* g1 = (const float*)d_in[13];
  const float* g2 = (const float*)d_in[14];
  float* xout = (float*)d_out;

  if (ws_size < 201351168u) return;   // need ~192 MB scratch

  char* ws = (char*)d_ws;
  u16*   wqkv_t = (u16*)(ws + 0);            // 25,165,824
  u16*   h1     = (u16*)(ws + 25165824);     // 16,777,216
  u16*   qkv    = (u16*)(ws + 41943040);     // 50,331,648
  u16*   vt     = (u16*)(ws + 92274688);     // 16,777,216
  u16*   o_     = (u16*)(ws + 109051904);    // 16,777,216
  u16*   wo_t   = (u16*)(ws + 125829120);    //  8,388,608
  u16*   w1_t   = (u16*)(ws + 134217728);    // 33,554,432
  u16*   w2_t   = (u16*)(ws + 167772160);    // 33,554,432
  float* bqkv   = (float*)(ws + 201326592);  //     24,576
  u16*   u_     = (u16*)(ws + 0);            // 67,108,864 (aliases dead prefix)
  u16*   h2     = vt;
  float* x2     = xout;

  tr64<<<dim3(2, 32, 16), 256, 0, stream>>>(wq, wqkv_t,                          E_, DH_, (size_t)E_ * DH_, (size_t)DH_ * E_);
  tr64<<<dim3(2, 32, 16), 256, 0, stream>>>(wk, wqkv_t + (size_t)E_ * E_,        E_, DH_, (size_t)E_ * DH_, (size_t)DH_ * E_);
  tr64<<<dim3(2, 32, 16), 256, 0, stream>>>(wv, wqkv_t + (size_t)2 * E_ * E_,    E_, DH_, (size_t)E_ * DH_, (size_t)DH_ * E_);
  tr64<<<dim3(32, 32, 1),  256, 0, stream>>>(wo, wo_t, E_, E_, 0, 0);
  tr64<<<dim3(128, 32, 1), 256, 0, stream>>>(w1, w1_t, E_, 4 * E_, 0, 0);
  tr64<<<dim3(32, 128, 1), 256, 0, stream>>>(w2, w2_t, 4 * E_, E_, 0, 0);
  bias_cat<<<24, 256, 0, stream>>>(bq, bk, bv, bqkv);

  rmsnorm_k<<<NTOK, 256, 0, stream>>>(x, g1, h1);
  // QKV: Q/K -> qkv, V -> vt (transposed, fused)
  gemm3<128, 256, 1, 3><<<(NTOK / 128) * (QKVN / 256), 512, 0, stream>>>(h1, wqkv_t, bqkv, nullptr, qkv, vt, NTOK, QKVN, E_);
  attn_k<<<B_ * H_ * (T_ / 16 / 8), 256, 0, stream>>>(qkv, vt, o_);
  gemm3<128, 256, 0, 1><<<(NTOK / 128) * (E_ / 256), 512, 0, stream>>>(o_, wo_t, bo, x, x2, nullptr, NTOK, E_, E_);
  rmsnorm_k<<<NTOK, 256, 0, stream>>>(x2, g2, h2);
  gemm3<256, 256, 1, 2><<<(NTOK / 256) * (4 * E_ / 256), 512, 0, stream>>>(h2, w1_t, b1, nullptr, u_, nullptr, NTOK, 4 * E_, E_);
  gemm3<128, 256, 0, 1><<<(NTOK / 128) * (E_ / 256), 512, 0, stream>>>(u_, w2_t, b2, x2, xout, nullptr, NTOK, E_, 4 * E_);
}

// Round 14
// 652.611 us; speedup vs baseline: 1.4073x; 1.0225x over previous
//
#include <hip/hip_runtime.h>
#include <hip/hip_bf16.h>

typedef unsigned short u16;
typedef unsigned int   u32;
typedef __attribute__((ext_vector_type(8))) short short8;
typedef __attribute__((ext_vector_type(4))) float f32x4;
typedef __attribute__((ext_vector_type(4))) unsigned short u16x4;

#define E_    2048
#define H_    16
#define DH_   128
#define B_    2
#define T_    2048
#define NTOK  4096      // B*T
#define QKVN  6144      // 3*E

#define VMCNT(n) asm volatile("s_waitcnt vmcnt(" #n ")" ::: "memory")
#define LGKM0()  asm volatile("s_waitcnt lgkmcnt(0)" ::: "memory")

__device__ __forceinline__ u16 f2bf(float f) {
  union { float f; u32 u; } v; v.f = f;
  u32 r = (v.u + 0x7FFFu + ((v.u >> 16) & 1u)) >> 16;
  return (u16)r;
}

// ---------------------------------------------------------------- prep_all: every weight transpose + bias concat, ONE launch
__device__ __forceinline__ void tr64_body(
    const float* __restrict__ ib, u16* __restrict__ ob,
    int R, int C, int r0, int c0, int tid, float (*t)[65])
{
  const int rr = tid >> 4;
  const int cc = (tid & 15) * 4;
  #pragma unroll
  for (int p = 0; p < 4; ++p) {
    const float4 v = *(const float4*)(ib + (size_t)(r0 + p * 16 + rr) * C + c0 + cc);
    t[cc + 0][p * 16 + rr] = v.x;
    t[cc + 1][p * 16 + rr] = v.y;
    t[cc + 2][p * 16 + rr] = v.z;
    t[cc + 3][p * 16 + rr] = v.w;
  }
  __syncthreads();
  const int wr = tid >> 3;
  const int wc = (tid & 7) * 8;
  #pragma unroll
  for (int p = 0; p < 2; ++p) {
    short8 s;
    #pragma unroll
    for (int j = 0; j < 8; ++j) s[j] = (short)f2bf(t[p * 32 + wr][wc + j]);
    *(short8*)(ob + (size_t)(c0 + p * 32 + wr) * R + r0 + wc) = s;
  }
}

__global__ __launch_bounds__(256) void prep_all(
    const float* __restrict__ wq, const float* __restrict__ wk, const float* __restrict__ wv,
    const float* __restrict__ wo, const float* __restrict__ w1, const float* __restrict__ w2,
    const float* __restrict__ bq, const float* __restrict__ bk, const float* __restrict__ bv,
    u16* __restrict__ wqkv_t, u16* __restrict__ wo_t, u16* __restrict__ w1_t, u16* __restrict__ w2_t,
    float* __restrict__ bqkv)
{
  __shared__ float t[64][65];
  const int bid = blockIdx.x;
  const int tid = threadIdx.x;
  if (bid < 3072) {
    // wq/wk/wv: per-head [E][DH] -> wqkv_t + sec*E*E, tiles (bx 0..1, by 0..31, z 0..15)
    const int sec = bid >> 10;
    const int tI  = bid & 1023;
    const int z   = tI >> 6;
    const int by  = (tI >> 1) & 31;
    const int bx  = tI & 1;
    const float* src = (sec == 0) ? wq : (sec == 1) ? wk : wv;
    tr64_body(src + (size_t)z * E_ * DH_,
              wqkv_t + (size_t)sec * E_ * E_ + (size_t)z * DH_ * E_,
              E_, DH_, by * 64, bx * 64, tid, t);
  } else if (bid < 4096) {
    const int tI = bid - 3072;              // wo [2048][2048], (32,32)
    tr64_body(wo, wo_t, E_, E_, (tI >> 5) * 64, (tI & 31) * 64, tid, t);
  } else if (bid < 8192) {
    const int tI = bid - 4096;              // w1 [2048][8192], (128,32)
    tr64_body(w1, w1_t, E_, 4 * E_, (tI >> 7) * 64, (tI & 127) * 64, tid, t);
  } else if (bid < 12288) {
    const int tI = bid - 8192;              // w2 [8192][2048], (32,128)
    tr64_body(w2, w2_t, 4 * E_, E_, (tI >> 5) * 64, (tI & 31) * 64, tid, t);
  } else {
    const int idx = (bid - 12288) * 256 + tid;   // bias concat, 24 blocks
    const float* bb = (idx < 2048) ? bq : (idx < 4096) ? bk : bv;
    bqkv[idx] = bb[idx & 2047];
  }
}

// ---------------------------------------------------------------- rmsnorm
__global__ __launch_bounds__(256) void rmsnorm_k(
    const float* __restrict__ x, const float* __restrict__ g, u16* __restrict__ o)
{
  const int row = blockIdx.x;
  const float4* xr = (const float4*)(x + (size_t)row * E_);
  const float4* gr = (const float4*)g;
  const int tid = threadIdx.x;
  float4 a0 = xr[tid], a1 = xr[tid + 256];
  float s = a0.x*a0.x + a0.y*a0.y + a0.z*a0.z + a0.w*a0.w
          + a1.x*a1.x + a1.y*a1.y + a1.z*a1.z + a1.w*a1.w;
  #pragma unroll
  for (int m = 1; m < 64; m <<= 1) s += __shfl_xor(s, m);
  __shared__ float wsum[4];
  if ((tid & 63) == 0) wsum[tid >> 6] = s;
  __syncthreads();
  float tot = wsum[0] + wsum[1] + wsum[2] + wsum[3];
  float rinv = rsqrtf(tot * (1.0f / E_) + 1e-8f);
  float4 g0 = gr[tid], g1 = gr[tid + 256];
  u16x4 o0, o1;
  o0[0] = f2bf(a0.x * g0.x * rinv); o0[1] = f2bf(a0.y * g0.y * rinv);
  o0[2] = f2bf(a0.z * g0.z * rinv); o0[3] = f2bf(a0.w * g0.w * rinv);
  o1[0] = f2bf(a1.x * g1.x * rinv); o1[1] = f2bf(a1.y * g1.y * rinv);
  o1[2] = f2bf(a1.z * g1.z * rinv); o1[3] = f2bf(a1.w * g1.w * rinv);
  u16x4* orow = (u16x4*)(o + (size_t)row * E_);
  orow[tid] = o0;
  orow[tid + 256] = o1;
}

__device__ __forceinline__ void gload_lds16(const void* g, u16* lds_base) {
  __builtin_amdgcn_global_load_lds(
      (const __attribute__((address_space(1))) u32*)g,
      (__attribute__((address_space(3))) u32*)lds_base, 16, 0, 0);
}

// ---------------------------------------------------------------- GEMM: R10-best. 512 thr, 3-buffer counted-vmcnt,
// single-region K-tile, XOR swizzle, MODE XCD partitioning.
// EPI: 0 bf16+bias, 1 f32+bias+resid, 2 bf16+bias+GELU,
//      3 QKV fused: Q/K cols -> out (bf16), V cols -> vtout transposed.
template<int BM, int BN, int MODE, int EPI>
__global__ __launch_bounds__(512, 2)
void gemm3(const u16* __restrict__ A, const u16* __restrict__ Bt,
           const float* __restrict__ bias, const float* __restrict__ resid,
           void* __restrict__ out, u16* __restrict__ vtout, int M, int N, int K)
{
  constexpr int WROWS = BM / 2;          // 128 or 64
  constexpr int WCOLS = BN / 4;          // 64
  constexpr int MR    = WROWS / 16;      // 8 or 4
  constexpr int BUF   = (BM + BN) * 32;  // u16 per K-tile buffer
  __shared__ __align__(16) u16 sh[3 * BUF];

  const int tid  = threadIdx.x;
  const int lane = tid & 63;
  const int l15  = lane & 15, lg = lane >> 4;
  const int w    = tid >> 6;
  const int wm   = w >> 2;
  const int wn   = w & 3;
  const int xs   = (l15 >> 1) & 3;

  const int nbx = N / BN;
  const int xcd = blockIdx.x & 7, j = blockIdx.x >> 3;
  int m0, n0;
  if constexpr (MODE == 1) {
    const int ncx = nbx >> 3;
    n0 = (xcd * ncx + j % ncx) * BN;
    m0 = (j / ncx) * BM;
  } else {
    const int nwg = nbx * (M / BM);
    const int sid = xcd * (nwg >> 3) + j;
    m0 = (sid / nbx) * BM;
    n0 = (sid % nbx) * BN;
  }

  const int r0 = tid >> 2;
  const int c0 = (((tid & 3) ^ ((tid >> 3) & 3)) * 8);
  const u16* gA  = A  + (size_t)(m0 + r0) * K + c0;
  const u16* gB  = Bt + (size_t)(n0 + r0) * K + c0;
  const u16* gA2 = gA + (size_t)128 * K;
  const u16* gB2 = gB + (size_t)128 * K;
  const int wub = (tid & ~63) * 8;

  f32x4 acc[MR][4] = {};
  const int NT = K >> 5;

  #pragma unroll
  for (int t = 0; t < 2; ++t) {
    u16* wb = sh + t * BUF;
    const int kS = t * 32;
    if constexpr (BM == 256) {
      gload_lds16(gA  + kS, wb + wub);
      gload_lds16(gA2 + kS, wb + 4096 + wub);
      gload_lds16(gB  + kS, wb + 8192 + wub);
      gload_lds16(gB2 + kS, wb + 12288 + wub);
    } else {
      gload_lds16(gA  + kS, wb + wub);
      gload_lds16(gB  + kS, wb + 4096 + wub);
      gload_lds16(gB2 + kS, wb + 8192 + wub);
    }
  }
  if constexpr (BM == 256) VMCNT(4); else VMCNT(3);
  __builtin_amdgcn_s_barrier();

  int i = 0;

#define KTILE(CUR, STG)                                                          \
  do {                                                                           \
    const u16* rb = sh + (CUR) * BUF;                                            \
    u16* wb = sh + (STG) * BUF;                                                  \
    const bool st = (i + 2 < NT);                                                \
    const int kS = (i + 2) << 5;                                                 \
    const int rem = NT - 1 - i;                                                  \
    if (st) {                                                                    \
      if constexpr (BM == 256) {                                                 \
        gload_lds16(gA  + kS, wb + wub);                                         \
        gload_lds16(gA2 + kS, wb + 4096 + wub);                                  \
        gload_lds16(gB  + kS, wb + 8192 + wub);                                  \
        gload_lds16(gB2 + kS, wb + 12288 + wub);                                 \
      } else {                                                                   \
        gload_lds16(gA  + kS, wb + wub);                                         \
        gload_lds16(gB  + kS, wb + 4096 + wub);                                  \
        gload_lds16(gB2 + kS, wb + 8192 + wub);                                  \
      }                                                                          \
    }                                                                            \
    short8 bf[4];                                                                \
    _Pragma("unroll")                                                            \
    for (int n = 0; n < 4; ++n)                                                  \
      bf[n] = *(const short8*)(rb + BM * 32 + (wn * WCOLS + n * 16 + l15) * 32 + ((lg ^ xs) * 8)); \
    _Pragma("unroll")                                                            \
    for (int mh = 0; mh < MR / 4; ++mh) {                                        \
      short8 af[4];                                                              \
      _Pragma("unroll")                                                          \
      for (int m = 0; m < 4; ++m)                                                \
        af[m] = *(const short8*)(rb + (wm * WROWS + (mh * 4 + m) * 16 + l15) * 32 + ((lg ^ xs) * 8)); \
      _Pragma("unroll")                                                          \
      for (int m = 0; m < 4; ++m)                                                \
        _Pragma("unroll")                                                        \
        for (int n = 0; n < 4; ++n)                                              \
          acc[mh * 4 + m][n] = __builtin_amdgcn_mfma_f32_16x16x32_bf16(af[m], bf[n], acc[mh * 4 + m][n], 0, 0, 0); \
    }                                                                            \
    if (rem >= 2) { if constexpr (BM == 256) { VMCNT(4); } else { VMCNT(3); } }  \
    else { VMCNT(0); }                                                           \
    __builtin_amdgcn_s_barrier();                                                \
    ++i;                                                                         \
  } while (0)

  const int trips = NT / 3;                 // NT = 64 or 256 -> remainder 1
  #pragma unroll 1
  for (int t = 0; t < trips; ++t) {
    KTILE(0, 2);
    KTILE(1, 0);
    KTILE(2, 1);
  }
  if (i < NT) KTILE(0, 2);
  if (i < NT) KTILE(1, 0);
#undef KTILE

  // ---- epilogue
  float bv[4];
  #pragma unroll
  for (int n = 0; n < 4; ++n) bv[n] = bias[n0 + wn * WCOLS + n * 16 + l15];

  if constexpr (EPI == 1) {
    #pragma unroll
    for (int n = 0; n < 4; ++n) {
      const int col = n0 + wn * WCOLS + n * 16 + l15;
      #pragma unroll
      for (int m = 0; m < MR; ++m)
        #pragma unroll
        for (int r = 0; r < 4; ++r) {
          const int row = m0 + wm * WROWS + m * 16 + lg * 4 + r;
          const size_t off = (size_t)row * N + col;
          ((float*)out)[off] = acc[m][n][r] + bv[n] + resid[off];
        }
    }
  } else if (EPI == 3 && n0 >= 4096) {
    // V section -> vt[b*16+h][d][t], via per-wave LDS transpose [64][64]
    u16* epb = sh + w * 4096;              // 8 waves x 8 KB = 64 KB <= 72 KB
    #pragma unroll
    for (int n = 0; n < 4; ++n)
      #pragma unroll
      for (int m = 0; m < MR; ++m)
        #pragma unroll
        for (int r = 0; r < 4; ++r)
          epb[(n * 16 + l15) * 64 + m * 16 + lg * 4 + r] = f2bf(acc[m][n][r] + bv[n]);
    LGKM0();
    const int colV0 = n0 - 4096 + wn * 64;
    const int hh = colV0 >> 7;
    const int db = colV0 & 127;
    const int tw = m0 + wm * WROWS;
    const int bb = tw >> 11;
    const int tb = tw & 2047;
    u16* vbase = vtout + ((size_t)(bb * 16 + hh) * 128 + db) * 2048 + tb;
    #pragma unroll
    for (int it = 0; it < 8; ++it) {
      const int c = it * 64 + lane;
      const int d = c >> 3, sl = c & 7;
      short8 s = *(const short8*)(epb + d * 64 + sl * 8);
      *(short8*)(vbase + (size_t)d * 2048 + sl * 8) = s;
    }
  } else {
    u16* ep = sh + w * 1024;
    #pragma unroll
    for (int m = 0; m < MR; ++m) {
      #pragma unroll
      for (int n = 0; n < 4; ++n)
        #pragma unroll
        for (int r = 0; r < 4; ++r) {
          float v = acc[m][n][r] + bv[n];
          if (EPI == 2) {
            float t = v * (0.79788456080286536f + 0.0356774081363231f * v * v);
            v = v / (1.0f + __expf(-2.0f * t));
          }
          ep[(lg * 4 + r) * 64 + n * 16 + l15] = f2bf(v);
        }
      LGKM0();
      const int row0 = m0 + wm * WROWS + m * 16;
      #pragma unroll
      for (int it = 0; it < 2; ++it) {
        const int ch = it * 64 + lane;
        const int rr = ch >> 3, c8 = ch & 7;
        short8 s = *(const short8*)(ep + rr * 64 + c8 * 8);
        *(short8*)((u16*)out + (size_t)(row0 + rr) * N + n0 + wn * WCOLS + c8 * 8) = s;
      }
      LGKM0();
    }
  }
}

// ---------------------------------------------------------------- flash attention (causal) + defer-max (T13)
__global__ __launch_bounds__(256) void attn_k(
    const u16* __restrict__ qkv, const u16* __restrict__ vt, u16* __restrict__ o)
{
  const int tid  = threadIdx.x;
  const int lane = tid & 63;
  const int w    = tid >> 6;
  const int l15  = lane & 15, lg = lane >> 4;
  const int bid  = blockIdx.x;
  const int pair = bid & 31;
  const int qt   = 15 - (bid >> 5);
  const int h    = pair & 15;
  const int b    = pair >> 4;
  const int Q0 = qt * 128;
  const int qw = Q0 + w * 32;

  __shared__ __align__(16) u16 Ks[2][64 * 128];
  __shared__ __align__(16) u16 Vs[2][128 * 64];
  __shared__ __align__(16) u16 Ps[4][32 * 64];

  const u16* qb  = qkv + (size_t)b * T_ * QKVN + h * DH_;
  const u16* kb  = qb + E_;
  const u16* vtb = vt + (size_t)(b * H_ + h) * DH_ * T_;

  short8 qf[2][4];
  #pragma unroll
  for (int qi = 0; qi < 2; ++qi)
    #pragma unroll
    for (int kk = 0; kk < 4; ++kk)
      qf[qi][kk] = *(const short8*)(qb + (size_t)(qw + qi * 16 + l15) * QKVN + kk * 32 + lg * 8);

  f32x4 oacc[2][8] = {};
  float m_[2][4], l_[2][4];
  #pragma unroll
  for (int qi = 0; qi < 2; ++qi)
    #pragma unroll
    for (int r = 0; r < 4; ++r) { m_[qi][r] = -1e30f; l_[qi][r] = 0.f; }

  const int xr = l15 & 7;
  const float scl = 0.08838834764831845f;
  const int nt = Q0 / 64 + 2;
  const int qmaxw = qw + 31;
  const int wub = (tid & ~63);

  const u16* kp[4]; const u16* vp[4];
  #pragma unroll
  for (int i = 0; i < 4; ++i) {
    int f = i * 256 + tid;
    int r = f >> 4, p = f & 15, c = p ^ (r & 7);
    kp[i] = kb + (size_t)r * QKVN + c * 8;
  }
  #pragma unroll
  for (int i = 0; i < 4; ++i) {
    int f = i * 256 + tid;
    int d = f >> 3, p = f & 7, c = p ^ (d & 7);
    vp[i] = vtb + (size_t)d * T_ + c * 8;
  }

  auto STAGEKV = [&](int s0, int bufi) {
    const size_t ko = (size_t)s0 * QKVN;
    #pragma unroll
    for (int i = 0; i < 4; ++i)
      gload_lds16(kp[i] + ko, &Ks[bufi][(i * 256 + wub) * 8]);
    #pragma unroll
    for (int i = 0; i < 4; ++i)
      gload_lds16(vp[i] + s0, &Vs[bufi][(i * 256 + wub) * 8]);
  };

  STAGEKV(0, 0);
  VMCNT(0);
  __builtin_amdgcn_s_barrier();

  #pragma unroll 1
  for (int st = 0; st < nt; ++st) {
    const int s0 = st * 64;
    const int cur = st & 1;
    if (st + 1 < nt) STAGEKV(s0 + 64, cur ^ 1);

    if (s0 <= qmaxw) {
      const u16* Kc = Ks[cur];
      const u16* Vc = Vs[cur];
      f32x4 sc[2][4] = {};
      __builtin_amdgcn_s_setprio(1);
      #pragma unroll
      for (int sj = 0; sj < 4; ++sj) {
        const int row = sj * 16 + l15;
        #pragma unroll
        for (int kk = 0; kk < 4; ++kk) {
          short8 kfr = *(const short8*)(Kc + row * 128 + (((kk * 4 + lg) ^ xr) * 8));
          sc[0][sj] = __builtin_amdgcn_mfma_f32_16x16x32_bf16(qf[0][kk], kfr, sc[0][sj], 0, 0, 0);
          sc[1][sj] = __builtin_amdgcn_mfma_f32_16x16x32_bf16(qf[1][kk], kfr, sc[1][sj], 0, 0, 0);
        }
      }
      __builtin_amdgcn_s_setprio(0);
      const bool needmask = (s0 + 63 > qw);
      #pragma unroll
      for (int qi = 0; qi < 2; ++qi)
        #pragma unroll
        for (int sj = 0; sj < 4; ++sj)
          #pragma unroll
          for (int r = 0; r < 4; ++r) {
            float v = sc[qi][sj][r] * scl;
            if (needmask) {
              int s = s0 + sj * 16 + l15;
              int q = qw + qi * 16 + lg * 4 + r;
              if (s > q) v = -1e30f;
            }
            sc[qi][sj][r] = v;
          }
      // ---- online softmax with defer-max (skip rescale when max growth <= 8)
      float tmax[2][4];
      #pragma unroll
      for (int qi = 0; qi < 2; ++qi) {
        #pragma unroll
        for (int r = 0; r < 4; ++r) {
          tmax[qi][r] = fmaxf(fmaxf(sc[qi][0][r], sc[qi][1][r]), fmaxf(sc[qi][2][r], sc[qi][3][r]));
          #pragma unroll
          for (int m = 1; m < 16; m <<= 1) tmax[qi][r] = fmaxf(tmax[qi][r], __shfl_xor(tmax[qi][r], m));
        }
      }
      bool grow = false;
      #pragma unroll
      for (int qi = 0; qi < 2; ++qi)
        #pragma unroll
        for (int r = 0; r < 4; ++r) grow |= (tmax[qi][r] > m_[qi][r] + 8.0f);
      if (__any(grow)) {
        #pragma unroll
        for (int qi = 0; qi < 2; ++qi) {
          float alpha[4];
          #pragma unroll
          for (int r = 0; r < 4; ++r) {
            float mn = fmaxf(m_[qi][r], tmax[qi][r]);
            alpha[r] = __expf(m_[qi][r] - mn);
            m_[qi][r] = mn;
            l_[qi][r] *= alpha[r];
          }
          #pragma unroll
          for (int dj = 0; dj < 8; ++dj)
            #pragma unroll
            for (int r = 0; r < 4; ++r) oacc[qi][dj][r] *= alpha[r];
        }
      }
      #pragma unroll
      for (int qi = 0; qi < 2; ++qi) {
        float rsum[4] = {0.f, 0.f, 0.f, 0.f};
        #pragma unroll
        for (int sj = 0; sj < 4; ++sj)
          #pragma unroll
          for (int r = 0; r < 4; ++r) {
            float p = __expf(sc[qi][sj][r] - m_[qi][r]);
            rsum[r] += p;
            const int row = qi * 16 + lg * 4 + r;
            const int ch  = (sj * 2 + (l15 >> 3)) ^ (row & 7);
            Ps[w][row * 64 + ch * 8 + (l15 & 7)] = f2bf(p);
          }
        #pragma unroll
        for (int r = 0; r < 4; ++r) {
          #pragma unroll
          for (int m = 1; m < 16; m <<= 1) rsum[r] += __shfl_xor(rsum[r], m);
          l_[qi][r] += rsum[r];
        }
      }
      __builtin_amdgcn_s_setprio(1);
      #pragma unroll
      for (int ks = 0; ks < 2; ++ks) {
        short8 pf0 = *(const short8*)(&Ps[w][l15 * 64 + (((ks * 4 + lg) ^ xr) * 8)]);
        short8 pf1 = *(const short8*)(&Ps[w][(16 + l15) * 64 + (((ks * 4 + lg) ^ xr) * 8)]);
        #pragma unroll
        for (int dj = 0; dj < 8; ++dj) {
          const int row = dj * 16 + l15;
          short8 vfr = *(const short8*)(Vc + row * 64 + (((ks * 4 + lg) ^ xr) * 8));
          oacc[0][dj] = __builtin_amdgcn_mfma_f32_16x16x32_bf16(pf0, vfr, oacc[0][dj], 0, 0, 0);
          oacc[1][dj] = __builtin_amdgcn_mfma_f32_16x16x32_bf16(pf1, vfr, oacc[1][dj], 0, 0, 0);
        }
      }
      __builtin_amdgcn_s_setprio(0);
    }
    VMCNT(0);
    __builtin_amdgcn_s_barrier();
  }

  float inv[2][4];
  #pragma unroll
  for (int qi = 0; qi < 2; ++qi)
    #pragma unroll
    for (int r = 0; r < 4; ++r) inv[qi][r] = 1.0f / l_[qi][r];
  u16* ob = o + (size_t)(b * T_ + qw) * E_ + h * DH_;
  #pragma unroll
  for (int qi = 0; qi < 2; ++qi)
    #pragma unroll
    for (int dj = 0; dj < 8; ++dj)
      #pragma unroll
      for (int r = 0; r < 4; ++r)
        ob[(size_t)(qi * 16 + lg * 4 + r) * E_ + dj * 16 + l15] = f2bf(oacc[qi][dj][r] * inv[qi][r]);
}

// ---------------------------------------------------------------- launch
extern "C" void kernel_launch(void* const* d_in, const int* in_sizes, int n_in,
                              void* d_out, int out_size, void* d_ws, size_t ws_size,
                              hipStream_t stream)
{
  const float* x  = (const float*)d_in[0];
  const float* wq = (const float*)d_in[1];
  const float* bq = (const float*)d_in[2];
  const float* wk = (const float*)d_in[3];
  const float* bk = (const float*)d_in[4];
  const float* wv = (const float*)d_in[5];
  const float* bv = (const float*)d_in[6];
  const float* wo = (const float*)d_in[7];
  const float* bo = (const float*)d_in[8];
  const float* w1 = (const float*)d_in[9];
  const float* b1 = (const float*)d_in[10];
  const float* w2 = (const float*)d_in[11];
  const float* b2 = (const float*)d_in[12];
  const float* g1 = (const float*)d_in[13];
  const float* g2 = (const float*)d_in[14];
  float* xout = (float*)d_out;

  if (ws_size < 201351168u) return;   // need ~192 MB scratch

  char* ws = (char*)d_ws;
  u16*   wqkv_t = (u16*)(ws + 0);            // 25,165,824
  u16*   h1     = (u16*)(ws + 25165824);     // 16,777,216
  u16*   qkv    = (u16*)(ws + 41943040);     // 50,331,648
  u16*   vt     = (u16*)(ws + 92274688);     // 16,777,216
  u16*   o_     = (u16*)(ws + 109051904);    // 16,777,216
  u16*   wo_t   = (u16*)(ws + 125829120);    //  8,388,608
  u16*   w1_t   = (u16*)(ws + 134217728);    // 33,554,432
  u16*   w2_t   = (u16*)(ws + 167772160);    // 33,554,432
  float* bqkv   = (float*)(ws + 201326592);  //     24,576
  u16*   u_     = (u16*)(ws + 0);            // 67,108,864 (aliases dead prefix)
  u16*   h2     = vt;
  float* x2     = xout;

  prep_all<<<12312, 256, 0, stream>>>(wq, wk, wv, wo, w1, w2, bq, bk, bv,
                                      wqkv_t, wo_t, w1_t, w2_t, bqkv);

  rmsnorm_k<<<NTOK, 256, 0, stream>>>(x, g1, h1);
  // QKV: Q/K -> qkv, V -> vt (transposed, fused)
  gemm3<128, 256, 1, 3><<<(NTOK / 128) * (QKVN / 256), 512, 0, stream>>>(h1, wqkv_t, bqkv, nullptr, qkv, vt, NTOK, QKVN, E_);
  attn_k<<<B_ * H_ * (T_ / 16 / 8), 256, 0, stream>>>(qkv, vt, o_);
  gemm3<128, 256, 0, 1><<<(NTOK / 128) * (E_ / 256), 512, 0, stream>>>(o_, wo_t, bo, x, x2, nullptr, NTOK, E_, E_);
  rmsnorm_k<<<NTOK, 256, 0, stream>>>(x2, g2, h2);
  gemm3<256, 256, 1, 2><<<(NTOK / 256) * (4 * E_ / 256), 512, 0, stream>>>(h2, w1_t, b1, nullptr, u_, nullptr, NTOK, 4 * E_, E_);
  gemm3<128, 256, 0, 1><<<(NTOK / 128) * (E_ / 256), 512, 0, stream>>>(u_, w2_t, b2, x2, xout, nullptr, NTOK, E_, 4 * E_);
}